// Round 1
// baseline (212.750 us; speedup 1.0000x reference)
//
#include <hip/hip_runtime.h>

// Layout facts (floats):
//   input  x: (2,4,4,4,1048576)  -> slice(b,i) base = b*67108864 + i*16777216
//   output  : (2, 4*262144, 64)  -> slice(b,i) base = b*67108864 + i*16777216
// float4 strides: batch 16777216, level 4194304.
//
// from_tb index maps (per-slice flat j as function of volume coords X,Y,Z):
//   i=0: j = Y*65536 + Z*256 + X
//   i=1: j = [(Z%4)*1024 + (Y>>2)*16 + (Z>>4)]*4096 + X*16 + ((Z>>2)&3)*4 + (Y&3)
//   i=2: j = (Z%16)*2^20 + (Y>>4)*2^16 + X*256 + (Z>>4)*16 + (Y&15)
//   i=3: j = ((Z%64)>>2)*2^20 + X*4096 + ((Z&3)*16+(Y>>6)*4+(Z>>6))*64 + (Y&63)
// downscale^i = (4^i)^3 box average (axis order preserved); tile = coord mod.
// final to_tb: u=(Z>>2)*4096+(Y>>2)*64+(X>>2); e=(X&3)*16+(Y&3)*4+(Z&3).

// ---------------- level 0: pure permutation via LDS tile ----------------
// WG = (Y_hi, Z_hi); loads 16 rows of 256 floats, writes 4096 consecutive floats.
__global__ __launch_bounds__(256) void k_l0(const float* __restrict__ in,
                                            float* __restrict__ out) {
    const int b = blockIdx.y;
    const int Y_hi = blockIdx.x >> 6, Z_hi = blockIdx.x & 63;
    const int tid = threadIdx.x;
    __shared__ float lds[16 * 260];   // row stride 260 (16B-aligned, spreads banks)
    const float4* in4 = (const float4*)in;
    float4* out4 = (float4*)out;
    const long in_b4 = (long)b * 16777216;  // level 0 offset = 0
#pragma unroll
    for (int k = 0; k < 4; ++k) {
        int idx = k * 256 + tid;          // 0..1023 float4s
        int r = idx >> 6;                 // row = Y_lo*4+Z_lo
        int col4 = idx & 63;
        int Y = Y_hi * 4 + (r >> 2), Z = Z_hi * 4 + (r & 3);
        float4 v = in4[in_b4 + (long)Y * 16384 + Z * 64 + col4];
        *(float4*)&lds[r * 260 + col4 * 4] = v;
    }
    __syncthreads();
    const long out_b4 = (long)b * 16777216 + (long)Z_hi * 65536 + Y_hi * 1024;
#pragma unroll
    for (int k = 0; k < 4; ++k) {
        int idx = k * 256 + tid;                       // output float4 index
        int X = ((idx >> 4) << 2) + ((tid >> 2) & 3);  // X_hi*4 + X_lo
        int row0 = (tid & 3) * 4;                      // Y_lo*4
        float4 v;
        v.x = lds[(row0 + 0) * 260 + X];
        v.y = lds[(row0 + 1) * 260 + X];
        v.z = lds[(row0 + 2) * 260 + X];
        v.w = lds[(row0 + 3) * 260 + X];
        out4[out_b4 + idx] = v;
    }
}

// ---------------- level 1 reduce: D1[64][64][64] per batch ----------------
// j = [dz*1024 + y'*16 + z'/4]*4096 + (4x'+dx)*16 + (z'%4)*4 + dy
// WG per t_low = y'*16 + z'/4; reads 4 regions (dz) of 4096 floats.
__global__ __launch_bounds__(256) void k_l1_red(const float* __restrict__ in,
                                                float* __restrict__ d1) {
    const int b = blockIdx.y;
    const int tlow = blockIdx.x;     // 0..1023
    const int tid = threadIdx.x;
    const float4* in4 = (const float4*)in;
    const long base4 = (long)b * 16777216 + 4194304;  // level 1 slice
    float acc[4] = {0.f, 0.f, 0.f, 0.f};
    for (int dz = 0; dz < 4; ++dz) {
        long rb = base4 + (long)(dz * 1024 + tlow) * 1024;
#pragma unroll
        for (int k = 0; k < 4; ++k) {
            float4 v = in4[rb + k * 256 + tid];  // float4 = 4 dy values, (X,p) fixed
            acc[k] += v.x + v.y + v.z + v.w;
        }
    }
#pragma unroll
    for (int k = 0; k < 4; ++k) {   // reduce over dx = tid bits 2..3
        acc[k] += __shfl_xor(acc[k], 4);
        acc[k] += __shfl_xor(acc[k], 8);
    }
    if ((tid & 12) == 0) {
        int yp = tlow >> 4;
        int zp = ((tlow & 15) << 2) + (tid & 3);
#pragma unroll
        for (int k = 0; k < 4; ++k) {
            int xp = k * 16 + (tid >> 4);
            d1[b * 262144 + xp * 4096 + yp * 64 + zp] = acc[k] * (1.0f / 64.0f);
        }
    }
}

// ---------------- level 1 broadcast (table 1MB/batch, L2-resident) --------
__global__ __launch_bounds__(256) void k_l1_bc(const float* __restrict__ d1,
                                               float* __restrict__ out) {
    const int b = blockIdx.y;
    const int tid = threadIdx.x;
    const float4* d14 = (const float4*)d1;
    float4* out4 = (float4*)out;
    const long ob = (long)b * 16777216 + 4194304;
    const int d1b = b * 65536;
#pragma unroll
    for (int k = 0; k < 4; ++k) {
        int o4 = blockIdx.x * 1024 + k * 256 + tid;
        int u = o4 >> 4;
        int Xl = (o4 >> 2) & 3, Yl = o4 & 3;
        int Xh = u & 63, Yh = (u >> 6) & 63, Zh = u >> 12;
        int x = (Xh & 15) * 4 + Xl, y = (Yh & 15) * 4 + Yl;
        out4[ob + o4] = d14[d1b + x * 1024 + y * 16 + (Zh & 15)];
    }
}

// ---------------- level 2 reduce: D2[16][16][16] per batch ----------------
// j = dz*2^20 + y'*65536 + (16x'+dx)*256 + z'*16 + dy ; WG per (y',x').
__global__ __launch_bounds__(256) void k_l2_red(const float* __restrict__ in,
                                                float* __restrict__ d2) {
    const int b = blockIdx.y;
    const int yp = blockIdx.x >> 4, xp = blockIdx.x & 15;
    const int tid = threadIdx.x;
    const float4* in4 = (const float4*)in;
    const long base4 = (long)b * 16777216 + 2 * 4194304 + yp * 16384 + xp * 1024;
    float acc = 0.f;
    for (int dz = 0; dz < 16; ++dz) {
        long rb = base4 + (long)dz * 262144;
#pragma unroll
        for (int k = 0; k < 4; ++k) {
            float4 v = in4[rb + k * 256 + tid];  // z' = (tid>>2)&15, fixed per thread
            acc += v.x + v.y + v.z + v.w;
        }
    }
    acc += __shfl_xor(acc, 1);   // reduce dy-quarters
    acc += __shfl_xor(acc, 2);
    __shared__ float red[64];
    if ((tid & 3) == 0) red[tid >> 2] = acc;   // index = wave*16 + z'
    __syncthreads();
    if (tid < 16) {
        float s = red[tid] + red[16 + tid] + red[32 + tid] + red[48 + tid];
        d2[b * 4096 + xp * 256 + yp * 16 + tid] = s * (1.0f / 4096.0f);
    }
}

// ---------------- level 2 broadcast (table 16KB -> LDS) -------------------
__global__ __launch_bounds__(256) void k_l2_bc(const float* __restrict__ d2,
                                               float* __restrict__ out) {
    const int b = blockIdx.y;
    const int tid = threadIdx.x;
    __shared__ float4 tab[1024];
    const float4* d24 = (const float4*)d2;
#pragma unroll
    for (int j = 0; j < 4; ++j) tab[j * 256 + tid] = d24[b * 1024 + j * 256 + tid];
    __syncthreads();
    float4* out4 = (float4*)out;
    const long ob = (long)b * 16777216 + 2 * 4194304;
#pragma unroll
    for (int k = 0; k < 4; ++k) {
        int o4 = blockIdx.x * 1024 + k * 256 + tid;
        int u = o4 >> 4;
        int Xl = (o4 >> 2) & 3, Yl = o4 & 3;
        int Xh = u & 63, Yh = (u >> 6) & 63, Zh = u >> 12;
        int x = (Xh & 3) * 4 + Xl, y = (Yh & 3) * 4 + Yl;
        out4[ob + o4] = tab[x * 64 + y * 4 + (Zh & 3)];
    }
}

// ---------------- level 3 reduce: partials then combine -------------------
// j = hi*2^20 + (x'*64+dx)*4096 + ((dz%4)*16 + c)*64 + dy,  c = y'*4+z'
// WG per (x', hi, dxg): 16 contiguous regions (dxl) = 64K floats.
__global__ __launch_bounds__(256) void k_l3_red(const float* __restrict__ in,
                                                float* __restrict__ p3) {
    const int b = blockIdx.y;
    const int bx = blockIdx.x;                 // x'(2b) hi(4b) dxg(2b)
    const int xp = bx >> 6, hi = (bx >> 2) & 15, dxg = bx & 3;
    const int tid = threadIdx.x;
    const float4* in4 = (const float4*)in;
    const long base4 = (long)b * 16777216 + 3 * 4194304 +
                       (long)hi * 262144 + xp * 65536 + dxg * 16384;
    float acc = 0.f;   // c = tid>>4, fixed per thread
    for (int k = 0; k < 64; ++k) {
        float4 v = in4[base4 + k * 256 + tid];
        acc += v.x + v.y + v.z + v.w;
    }
    acc += __shfl_xor(acc, 1);
    acc += __shfl_xor(acc, 2);
    acc += __shfl_xor(acc, 4);
    acc += __shfl_xor(acc, 8);
    __shared__ float red[16];
    if ((tid & 15) == 0) red[tid >> 4] = acc;  // one writer per c
    __syncthreads();
    if (tid < 16)
        p3[((b * 4 + xp) * 64 + (bx & 63)) * 16 + tid] = red[tid];
}

__global__ __launch_bounds__(128) void k_l3_fin(const float* __restrict__ p3,
                                                float* __restrict__ d3) {
    const int tid = threadIdx.x;               // = b*64 + x'*16 + c
    const int b = tid >> 6, xp = (tid >> 4) & 3, c = tid & 15;
    float s = 0.f;
    for (int g = 0; g < 64; ++g) s += p3[((b * 4 + xp) * 64 + g) * 16 + c];
    d3[tid] = s * (1.0f / 262144.0f);
}

// ---------------- level 3 broadcast: same 64-float row everywhere ---------
__global__ __launch_bounds__(256) void k_l3_bc(const float* __restrict__ d3,
                                               float* __restrict__ out) {
    const int b = blockIdx.y;
    const int tid = threadIdx.x;
    const float4* d34 = (const float4*)d3;
    const float4 v = d34[b * 16 + (tid & 15)]; // e4 = o4%16 = tid%16 for all k
    float4* out4 = (float4*)out;
    const long ob = (long)b * 16777216 + 3 * 4194304;
#pragma unroll
    for (int k = 0; k < 4; ++k)
        out4[ob + blockIdx.x * 1024 + k * 256 + tid] = v;
}

extern "C" void kernel_launch(void* const* d_in, const int* in_sizes, int n_in,
                              void* d_out, int out_size, void* d_ws, size_t ws_size,
                              hipStream_t stream) {
    const float* in = (const float*)d_in[0];
    float* out = (float*)d_out;
    float* ws = (float*)d_ws;
    float* d1 = ws;                          // 2*262144 floats (2 MB)
    float* d2 = ws + 524288;                 // 2*4096
    float* p3 = ws + 524288 + 8192;          // 2*4*64*16 = 8192
    float* d3 = ws + 524288 + 8192 + 8192;   // 128
    dim3 thr(256);
    k_l0    <<<dim3(4096, 2), thr, 0, stream>>>(in, out);
    k_l1_red<<<dim3(1024, 2), thr, 0, stream>>>(in, d1);
    k_l1_bc <<<dim3(4096, 2), thr, 0, stream>>>(d1, out);
    k_l2_red<<<dim3(256, 2),  thr, 0, stream>>>(in, d2);
    k_l2_bc <<<dim3(4096, 2), thr, 0, stream>>>(d2, out);
    k_l3_red<<<dim3(256, 2),  thr, 0, stream>>>(in, p3);
    k_l3_fin<<<1, 128, 0, stream>>>(p3, d3);
    k_l3_bc <<<dim3(4096, 2), thr, 0, stream>>>(d3, out);
}